// Round 15
// baseline (113.425 us; speedup 1.0000x reference)
//
#include <hip/hip_runtime.h>
#include <hip/hip_bf16.h>

#define B_    4
#define C_    64
#define MVOX  32768      // 32*32*32
#define NATOM 64
#define EMB_  128

typedef __attribute__((ext_vector_type(8)))  __bf16 bf16x8;
typedef __attribute__((ext_vector_type(4)))  float  f32x4;
typedef __attribute__((ext_vector_type(16))) float  f32x16;
typedef __attribute__((ext_vector_type(8)))  unsigned short ushort8;

typedef __attribute__((address_space(1))) const unsigned int gas_u32;
typedef __attribute__((address_space(3))) unsigned int las_u32;

static __device__ __forceinline__ unsigned short bf16u(float f) {
  __hip_bfloat16 h = __float2bfloat16(f);
  return *(unsigned short*)&h;
}

// ---------------------------------------------------------------------------
// Kernel 0: weight prep (unchanged).
// ---------------------------------------------------------------------------
__global__ __launch_bounds__(256) void wprep_kernel(
    const float* __restrict__ Wc, const float* __restrict__ Wq,
    const float* __restrict__ Wo, const float* __restrict__ Wk,
    const float* __restrict__ Wv,
    __hip_bfloat16* __restrict__ Wt4, __hip_bfloat16* __restrict__ Wqb,
    __hip_bfloat16* __restrict__ Wob, __hip_bfloat16* __restrict__ Wkb,
    __hip_bfloat16* __restrict__ Wvb) {
  const int i = blockIdx.x * 256 + threadIdx.x;
  if (i < 110592) {                                   // conv weights
    const int tap = i >> 12;
    const int coh = (i >> 11) & 1;
    const int ks  = (i >> 9) & 3;
    const int l   = (i >> 3) & 63;
    const int j   = i & 7;
    const int co  = coh * 32 + (l & 31);
    const int ci  = ks * 16 + ((l >> 5) << 3) + j;
    Wt4[i] = __float2bfloat16(Wc[(co * C_ + ci) * 27 + tap]);
  } else if (i < 114688) {                            // Wq (scaled)
    const int i2 = i - 110592;
    const int nf = (i2 >> 10) & 3;
    const int kk = (i2 >> 9) & 1;
    const int l  = (i2 >> 3) & 63;
    const int j  = i2 & 7;
    const int co = nf * 16 + (l & 15);
    const int ci = kk * 32 + ((l >> 4) << 3) + j;
    Wqb[i2] = __float2bfloat16(Wq[co * C_ + ci] * 0.3535533905932738f);
  } else if (i < 118784) {                            // Wo
    const int i3 = i - 114688;
    const int nf = (i3 >> 10) & 3;
    const int kk = (i3 >> 9) & 1;
    const int l  = (i3 >> 3) & 63;
    const int j  = i3 & 7;
    const int co = nf * 16 + (l & 15);
    const int ci = kk * 32 + ((l >> 4) << 3) + j;
    Wob[i3] = __float2bfloat16(Wo[co * C_ + ci]);
  } else if (i < 135168) {                            // Wk / Wv B-frags
    const int i4 = (i - 118784) & 8191;
    const bool is_v = (i - 118784) >= 8192;
    const int ch = i4 >> 12;
    const int kk = (i4 >> 9) & 7;
    const int l  = (i4 >> 3) & 63;
    const int j  = i4 & 7;
    const int c  = ch * 32 + (l & 31);
    const int e  = kk * 16 + ((l >> 5) << 3) + j;
    const float v = (is_v ? Wv : Wk)[c * EMB_ + e];
    (is_v ? Wvb : Wkb)[i4] = __float2bfloat16(v);
  }
}

// ---------------------------------------------------------------------------
// Kernel 1: K/V projection + attn fragment-buffer emission (unchanged).
// ---------------------------------------------------------------------------
__global__ __launch_bounds__(256) void kv_kernel(
    const float* __restrict__ mol,
    const __hip_bfloat16* __restrict__ Wkb, const float* __restrict__ bk,
    const __hip_bfloat16* __restrict__ Wvb, const float* __restrict__ bv,
    unsigned short* __restrict__ kfb, unsigned short* __restrict__ vfb) {
  __shared__ float smol[NATOM][132];
  __shared__ float res[2][NATOM][68];

  const int b    = blockIdx.x;
  const int tid  = threadIdx.x;
  const int lane = tid & 63;
  const int w    = tid >> 6;
  const int kvw  = w >> 1;
  const int ah   = w & 1;

  for (int i = tid; i < 2048; i += 256) {
    const int a = i >> 4, cb = (i & 15) * 8;
    const f32x4 v0 = *(const f32x4*)&mol[(size_t)(b * NATOM + a) * EMB_ + cb];
    const f32x4 v1 = *(const f32x4*)&mol[(size_t)(b * NATOM + a) * EMB_ + cb + 4];
    *(f32x4*)&smol[a][cb]     = v0;
    *(f32x4*)&smol[a][cb + 4] = v1;
  }
  __syncthreads();

  const __hip_bfloat16* Wb   = kvw ? Wvb : Wkb;
  const float*          bias = kvw ? bv : bk;

  f32x16 acc[2];
  #pragma unroll
  for (int ch = 0; ch < 2; ++ch)
    #pragma unroll
    for (int r = 0; r < 16; ++r) acc[ch][r] = 0.f;

  const int a = ah * 32 + (lane & 31);
  #pragma unroll
  for (int kk = 0; kk < 8; ++kk) {
    const int e0 = kk * 16 + ((lane >> 5) << 3);
    ushort8 au;
    #pragma unroll
    for (int j = 0; j < 8; ++j) au[j] = bf16u(smol[a][e0 + j]);
    const bf16x8 af = __builtin_bit_cast(bf16x8, au);
    #pragma unroll
    for (int ch = 0; ch < 2; ++ch) {
      const bf16x8 bf = *(const bf16x8*)(Wb + (((ch * 8 + kk) << 6) + lane) * 8);
      acc[ch] = __builtin_amdgcn_mfma_f32_32x32x16_bf16(af, bf, acc[ch], 0, 0, 0);
    }
  }

  #pragma unroll
  for (int ch = 0; ch < 2; ++ch) {
    const int c = ch * 32 + (lane & 31);
    const float bb = bias[c];
    #pragma unroll
    for (int r = 0; r < 16; ++r) {
      const int ar = ah * 32 + (r & 3) + 8 * (r >> 2) + 4 * (lane >> 5);
      res[kvw][ar][c] = acc[ch][r] + bb;
    }
  }
  __syncthreads();

  #pragma unroll
  for (int t = 0; t < 8; ++t) {
    const int idx = t * 256 + tid;
    const int h = idx >> 8, aa = (idx >> 6) & 3, ln = idx & 63;
    const int qd = ln >> 4, l15 = ln & 15;
    ushort8 au;
    if (qd == 0) {
      #pragma unroll
      for (int j = 0; j < 8; ++j) au[j] = bf16u(res[0][aa * 16 + l15][h * 8 + j]);
    } else {
      #pragma unroll
      for (int j = 0; j < 8; ++j) au[j] = 0;
    }
    *(ushort8*)(kfb + (size_t)(((b * 8 + h) * 4 + aa) * 64 + ln) * 8) = au;
  }
  #pragma unroll
  for (int t = 0; t < 4; ++t) {
    const int idx = t * 256 + tid;
    const int h = idx >> 7, s = (idx >> 6) & 1, ln = idx & 63;
    const int qd = ln >> 4, l15 = ln & 15;
    ushort8 au;
    #pragma unroll
    for (int j = 0; j < 8; ++j) {
      const int atom = (2 * s + (j >> 2)) * 16 + qd * 4 + (j & 3);
      au[j] = bf16u(res[1][atom][h * 8 + (l15 & 7)]);
    }
    *(ushort8*)(vfb + (size_t)(((b * 8 + h) * 2 + s) * 64 + ln) * 8) = au;
  }
}

// ---------------------------------------------------------------------------
// Kernel 2: fully-MFMA fused attention, fragment-fed (unchanged).
// ---------------------------------------------------------------------------
__global__ __launch_bounds__(512, 4) void attn_kernel(
    const float* __restrict__ x,
    const unsigned short* __restrict__ kfb, const unsigned short* __restrict__ vfb,
    const int* __restrict__ batch_nodes,
    const __hip_bfloat16* __restrict__ Wqb, const float* __restrict__ bq,
    const __hip_bfloat16* __restrict__ Wob, const float* __restrict__ bo,
    __hip_bfloat16* __restrict__ omid) {
  __shared__ float buf[64 * C_];     // 16 KB, multi-phase

  const int b    = blockIdx.y;
  const int m0   = blockIdx.x * 64;
  const int tid  = threadIdx.x;
  const int lane = tid & 63;
  const int w    = __builtin_amdgcn_readfirstlane(tid >> 6);   // 0..7
  const int h    = w;
  const int quad = lane >> 4;
  const int l15  = lane & 15;
  const int vq   = w & 3;
  const int cq   = w >> 2;

  bf16x8 kf[4], vf[2];
  #pragma unroll
  for (int a = 0; a < 4; ++a)
    kf[a] = __builtin_bit_cast(bf16x8,
        *(const ushort8*)(kfb + (size_t)(((b * 8 + h) * 4 + a) * 64 + lane) * 8));
  #pragma unroll
  for (int s = 0; s < 2; ++s)
    vf[s] = __builtin_bit_cast(bf16x8,
        *(const ushort8*)(vfb + (size_t)(((b * 8 + h) * 2 + s) * 64 + lane) * 8));

  #pragma unroll
  for (int j = 0; j < 2; ++j) {
    const int cidx = w * 2 + j;
    const int c  = cidx * 4 + (lane >> 4);
    const int v4 = (lane & 15) * 4;
    const float* gsrc = x + (size_t)(b * C_ + c) * MVOX + m0 + v4;
    __builtin_amdgcn_global_load_lds((gas_u32*)gsrc,
                                     (las_u32*)&buf[cidx * 256], 16, 0, 0);
  }
  __syncthreads();

  f32x4 qacc[2];
  {
    bf16x8 af[2];
    #pragma unroll
    for (int kk = 0; kk < 2; ++kk) {
      ushort8 au;
      #pragma unroll
      for (int j = 0; j < 8; ++j)
        au[j] = bf16u(buf[(kk * 32 + quad * 8 + j) * 64 + vq * 16 + l15]);
      af[kk] = __builtin_bit_cast(bf16x8, au);
    }
    #pragma unroll
    for (int nf2 = 0; nf2 < 2; ++nf2) {
      const int nf = cq * 2 + nf2;
      const float bqv = bq[nf * 16 + l15] * 0.3535533905932738f;
      qacc[nf2] = {bqv, bqv, bqv, bqv};
      #pragma unroll
      for (int kk = 0; kk < 2; ++kk) {
        const bf16x8 bf = *(const bf16x8*)(Wqb + (((nf * 2 + kk) << 6) + lane) * 8);
        qacc[nf2] = __builtin_amdgcn_mfma_f32_16x16x32_bf16(af[kk], bf, qacc[nf2], 0, 0, 0);
      }
    }
  }
  __syncthreads();

  unsigned short* qb = (unsigned short*)buf;
  #pragma unroll
  for (int nf2 = 0; nf2 < 2; ++nf2) {
    const int co = (cq * 2 + nf2) * 16 + l15;
    #pragma unroll
    for (int r = 0; r < 4; ++r) {
      const int vr = vq * 16 + quad * 4 + r;
      qb[vr * 64 + (((co >> 3) ^ (vr & 7)) << 3) + (co & 7)] = bf16u(qacc[nf2][r]);
    }
  }
  __syncthreads();

  const int nv = batch_nodes[b];
  unsigned short* ob = (unsigned short*)buf + 4096;

  f32x4 oacc[4];
  #pragma unroll
  for (int v = 0; v < 4; ++v)
    #pragma unroll
    for (int r = 0; r < 4; ++r) oacc[v][r] = 0.f;

  const f32x4 zero4 = {0.f, 0.f, 0.f, 0.f};
  #pragma unroll
  for (int v = 0; v < 4; ++v) {
    const int qrow = v * 16 + l15;
    const bf16x8 qf = __builtin_bit_cast(bf16x8,
        *(const ushort8*)&qb[qrow * 64 + ((h ^ (qrow & 7)) << 3)]);

    f32x4 st[4];
    #pragma unroll
    for (int a = 0; a < 4; ++a)
      st[a] = __builtin_amdgcn_mfma_f32_16x16x32_bf16(kf[a], qf, zero4, 0, 0, 0);

    float m = -1e30f;
    #pragma unroll
    for (int a = 0; a < 4; ++a)
      #pragma unroll
      for (int r = 0; r < 4; ++r) {
        const int atom = a * 16 + quad * 4 + r;
        const float val = (atom < nv) ? st[a][r] : -1e30f;
        st[a][r] = val;
        m = fmaxf(m, val);
      }
    m = fmaxf(m, __shfl_xor(m, 16, 64));
    m = fmaxf(m, __shfl_xor(m, 32, 64));
    float ssum = 0.f;
    #pragma unroll
    for (int a = 0; a < 4; ++a)
      #pragma unroll
      for (int r = 0; r < 4; ++r) {
        const float p = __expf(st[a][r] - m);
        st[a][r] = p;
        ssum += p;
      }
    ssum += __shfl_xor(ssum, 16, 64);
    ssum += __shfl_xor(ssum, 32, 64);
    const float inv = 1.f / ssum;

    #pragma unroll
    for (int s = 0; s < 2; ++s) {
      ushort8 pu;
      #pragma unroll
      for (int j = 0; j < 8; ++j)
        pu[j] = bf16u(st[2 * s + (j >> 2)][j & 3] * inv);
      const bf16x8 pa = __builtin_bit_cast(bf16x8, pu);
      oacc[v] = __builtin_amdgcn_mfma_f32_16x16x32_bf16(pa, vf[s], oacc[v], 0, 0, 0);
    }
  }

  if (l15 < 8) {
    #pragma unroll
    for (int v = 0; v < 4; ++v)
      #pragma unroll
      for (int r = 0; r < 4; ++r) {
        const int vxr = v * 16 + quad * 4 + r;
        ob[vxr * 64 + ((h ^ (vxr & 7)) << 3) + l15] = bf16u(oacc[v][r]);
      }
  }
  __syncthreads();

  {
    bf16x8 af[2];
    #pragma unroll
    for (int kk = 0; kk < 2; ++kk) {
      const int row = vq * 16 + l15;
      af[kk] = __builtin_bit_cast(bf16x8,
          *(const ushort8*)&ob[row * 64 + (((kk * 4 + quad) ^ (row & 7)) << 3)]);
    }
    f32x4 oac[2];
    #pragma unroll
    for (int nf2 = 0; nf2 < 2; ++nf2) {
      const int nf = cq * 2 + nf2;
      const float bov = bo[nf * 16 + l15];
      oac[nf2] = {bov, bov, bov, bov};
      #pragma unroll
      for (int kk = 0; kk < 2; ++kk) {
        const bf16x8 bf = *(const bf16x8*)(Wob + (((nf * 2 + kk) << 6) + lane) * 8);
        oac[nf2] = __builtin_amdgcn_mfma_f32_16x16x32_bf16(af[kk], bf, oac[nf2], 0, 0, 0);
      }
    }
    __syncthreads();
    unsigned short* osb = (unsigned short*)buf;
    #pragma unroll
    for (int nf2 = 0; nf2 < 2; ++nf2) {
      const int co = (cq * 2 + nf2) * 16 + l15;
      #pragma unroll
      for (int r = 0; r < 4; ++r) {
        const int vr = vq * 16 + quad * 4 + r;
        osb[vr * 64 + (((co >> 3) ^ (vr & 7)) << 3) + (co & 7)] =
            bf16u(fmaxf(oac[nf2][r], 0.f));
      }
    }
  }
  __syncthreads();

  *(ushort8*)(omid + (size_t)(b * MVOX + m0) * C_ + tid * 8) =
      *(const ushort8*)&((unsigned short*)buf)[tid * 8];
}

// ---------------------------------------------------------------------------
// Kernel 3: conv3d 3x3x3 circular, implicit-GEMM mfma_f32_32x32x16_bf16.
// R15: LDS-traffic halving. Block = 128 thr / 2 waves, 2x2 spatial, 64 KB
// halo. Wave = 2 x-lines x ALL 64 co (M=64, N=64 tile): per tap 8 B-reads +
// 8 W-loads + 16 MFMA (1.0 KB operand/MFMA vs R11's 1.5; no duplicate
// B-reads across waves). Load->use slack = 16 MFMA = 128cy. 2 blocks/CU.
// ---------------------------------------------------------------------------
#define LOADB(dst, DX, DY, DZ)                                              \
  {                                                                         \
    const int zp_ = ((lane & 31) + (DZ) + 31) & 31;                         \
    const int sw_ = zp_ & 7;                                                \
    _Pragma("unroll")                                                       \
    for (int ks_ = 0; ks_ < 4; ++ks_) {                                     \
      const int phys_ = (ks_ * 2 + (lane >> 5)) ^ sw_;                      \
      _Pragma("unroll")                                                     \
      for (int xl_ = 0; xl_ < 2; ++xl_) {                                   \
        const int hl_ = (xl_ + (DX)) * 4 + (wy + (DY));                     \
        (dst)[xl_ * 4 + ks_] =                                              \
            *(const bf16x8*)&halo[((hl_ * 32 + zp_) * 8 + phys_) * 8];      \
      }                                                                     \
    }                                                                       \
  }

#define LOADW(T2)                                                           \
  _Pragma("unroll")                                                         \
  for (int f_ = 0; f_ < 8; ++f_)                                            \
    wf[(T2) % 3][f_] = *(const bf16x8*)(                                    \
        Wt4 + ((((T2) * 2 + (f_ >> 2)) * 4 + (f_ & 3)) << 9) + lane * 8);

#define DOMFMA(src, T)                                                      \
  _Pragma("unroll")                                                         \
  for (int ks_ = 0; ks_ < 4; ++ks_)                                         \
    _Pragma("unroll")                                                       \
    for (int xl_ = 0; xl_ < 2; ++xl_)                                       \
      _Pragma("unroll")                                                     \
      for (int ch_ = 0; ch_ < 2; ++ch_)                                     \
        acc[xl_][ch_] = __builtin_amdgcn_mfma_f32_32x32x16_bf16(            \
            wf[(T) % 3][ch_ * 4 + ks_], (src)[xl_ * 4 + ks_],               \
            acc[xl_][ch_], 0, 0, 0);

__global__ __launch_bounds__(128, 1) void conv_kernel(
    const __hip_bfloat16* __restrict__ omid,
    const __hip_bfloat16* __restrict__ Wt4,
    const float* __restrict__ bc,
    const float* __restrict__ xin,
    float* __restrict__ out) {
  __shared__ __hip_bfloat16 halo[512 * 64];   // 64 KB

  const int b    = blockIdx.y;
  const int x0   = (blockIdx.x >> 4) * 2;
  const int y0   = (blockIdx.x & 15) * 2;
  const int tid  = threadIdx.x;
  const int lane = tid & 63;
  const int wy   = tid >> 6;          // 0..1: wave's y-line within the 2x2

  // --- halo staging: 64 chunks x 1KB, each wave stages 32 ---
  {
    const __hip_bfloat16* src = omid + (size_t)b * MVOX * C_;
    #pragma unroll
    for (int n = 0; n < 32; ++n) {
      const int chunk = wy * 32 + n;
      const int li = chunk >> 2;                 // halo line 0..15
      const int zb = (chunk & 3) * 8;
      const int gx = (x0 - 1 + (li >> 2)) & 31;
      const int gy = (y0 - 1 + (li & 3)) & 31;
      const __hip_bfloat16* gsrc = src + (size_t)(gx * 1024 + gy * 32 + zb) * C_ + lane * 8;
      __builtin_amdgcn_global_load_lds((gas_u32*)gsrc,
                                       (las_u32*)&halo[chunk * 512], 16, 0, 0);
    }
  }

  // --- weight ring (3 slots, 2-tap lookahead): taps 0,1 prefetched ---
  bf16x8 wf[3][8];
  LOADW(0);
  LOADW(1);
  __syncthreads();   // halo staged

  f32x16 acc[2][2];  // [x-line][co-half]: 64 co x 64 vox per wave
  #pragma unroll
  for (int xl = 0; xl < 2; ++xl)
    #pragma unroll
    for (int ch = 0; ch < 2; ++ch)
      #pragma unroll
      for (int r = 0; r < 16; ++r) acc[xl][ch][r] = 0.f;

  // --- B-fragment double buffer (1-tap lookahead; slack = 16 MFMA) ---
  bf16x8 bA[8], bB[8];
  LOADB(bA, 0, 0, 0);   // tap 0

  #pragma unroll
  for (int t = 0; t < 27; ++t) {
    const int tn = t + 1;
    if (tn < 27) {
      if ((t & 1) == 0) LOADB(bB, tn / 9, (tn / 3) % 3, tn % 3)
      else              LOADB(bA, tn / 9, (tn / 3) % 3, tn % 3)
    }
    if (t + 2 < 27) LOADW(t + 2);
    if ((t & 1) == 0) DOMFMA(bA, t)
    else              DOMFMA(bB, t)
  }

  // --- epilogue: relu(acc+bias) + residual; wave writes 2 lines x 64 co ---
  const int z = lane & 31;
  const int gy = y0 + wy;
  #pragma unroll
  for (int xl = 0; xl < 2; ++xl) {
    const int gx = x0 + xl;
    #pragma unroll
    for (int ch = 0; ch < 2; ++ch) {
      #pragma unroll
      for (int r = 0; r < 16; ++r) {
        const int co = ch * 32 + (r & 3) + 8 * (r >> 2) + 4 * (lane >> 5);
        const size_t idx = ((size_t)(b * C_ + co)) * MVOX + gx * 1024 + gy * 32 + z;
        out[idx] = fmaxf(acc[xl][ch][r] + bc[co], 0.f) + xin[idx];
      }
    }
  }
}

// ---------------------------------------------------------------------------
extern "C" void kernel_launch(void* const* d_in, const int* in_sizes, int n_in,
                              void* d_out, int out_size, void* d_ws, size_t ws_size,
                              hipStream_t stream) {
  const float* x   = (const float*)d_in[0];
  const float* mol = (const float*)d_in[1];
  const int*   bn  = (const int*)  d_in[2];
  const float* Wq  = (const float*)d_in[3];
  const float* bq  = (const float*)d_in[4];
  const float* Wk  = (const float*)d_in[5];
  const float* bk  = (const float*)d_in[6];
  const float* Wv  = (const float*)d_in[7];
  const float* bv  = (const float*)d_in[8];
  const float* Wo  = (const float*)d_in[9];
  const float* bo  = (const float*)d_in[10];
  const float* Wc  = (const float*)d_in[11];
  const float* bc  = (const float*)d_in[12];
  float* out = (float*)d_out;

  char* ws = (char*)d_ws;
  __hip_bfloat16* omid = (__hip_bfloat16*)ws;                     // 16,777,216 B
  __hip_bfloat16* Wt4  = (__hip_bfloat16*)(ws + 16777216);        // 221,184 B
  __hip_bfloat16* Wqb  = (__hip_bfloat16*)(ws + 16998400);        // 8,192 B
  __hip_bfloat16* Wob  = (__hip_bfloat16*)(ws + 17006592);        // 8,192 B
  __hip_bfloat16* Wkb  = (__hip_bfloat16*)(ws + 17014784);        // 16,384 B
  __hip_bfloat16* Wvb  = (__hip_bfloat16*)(ws + 17031168);        // 16,384 B
  unsigned short* kfb  = (unsigned short*)(ws + 17047552);        // 131,072 B
  unsigned short* vfb  = (unsigned short*)(ws + 17178624);        // 65,536 B

  wprep_kernel<<<dim3(528), 256, 0, stream>>>(Wc, Wq, Wo, Wk, Wv,
                                              Wt4, Wqb, Wob, Wkb, Wvb);
  kv_kernel<<<dim3(B_), 256, 0, stream>>>(mol, Wkb, bk, Wvb, bv, kfb, vfb);
  attn_kernel<<<dim3(MVOX / 64, B_), 512, 0, stream>>>(x, kfb, vfb, bn, Wqb, bq, Wob, bo, omid);
  conv_kernel<<<dim3(256, B_), 128, 0, stream>>>(omid, Wt4, bc, x, out);
}

// Round 16
// 90.550 us; speedup vs baseline: 1.2526x; 1.2526x over previous
//
#include <hip/hip_runtime.h>
#include <hip/hip_bf16.h>

#define B_    4
#define C_    64
#define MVOX  32768      // 32*32*32
#define NATOM 64
#define EMB_  128

typedef __attribute__((ext_vector_type(8)))  __bf16 bf16x8;
typedef __attribute__((ext_vector_type(4)))  float  f32x4;
typedef __attribute__((ext_vector_type(16))) float  f32x16;
typedef __attribute__((ext_vector_type(8)))  unsigned short ushort8;

typedef __attribute__((address_space(1))) const unsigned int gas_u32;
typedef __attribute__((address_space(3))) unsigned int las_u32;

static __device__ __forceinline__ unsigned short bf16u(float f) {
  __hip_bfloat16 h = __float2bfloat16(f);
  return *(unsigned short*)&h;
}

// ---------------------------------------------------------------------------
// Kernel 0: weight prep (unchanged).
// ---------------------------------------------------------------------------
__global__ __launch_bounds__(256) void wprep_kernel(
    const float* __restrict__ Wc, const float* __restrict__ Wq,
    const float* __restrict__ Wo, const float* __restrict__ Wk,
    const float* __restrict__ Wv,
    __hip_bfloat16* __restrict__ Wt4, __hip_bfloat16* __restrict__ Wqb,
    __hip_bfloat16* __restrict__ Wob, __hip_bfloat16* __restrict__ Wkb,
    __hip_bfloat16* __restrict__ Wvb) {
  const int i = blockIdx.x * 256 + threadIdx.x;
  if (i < 110592) {                                   // conv weights
    const int tap = i >> 12;
    const int coh = (i >> 11) & 1;
    const int ks  = (i >> 9) & 3;
    const int l   = (i >> 3) & 63;
    const int j   = i & 7;
    const int co  = coh * 32 + (l & 31);
    const int ci  = ks * 16 + ((l >> 5) << 3) + j;
    Wt4[i] = __float2bfloat16(Wc[(co * C_ + ci) * 27 + tap]);
  } else if (i < 114688) {                            // Wq (scaled)
    const int i2 = i - 110592;
    const int nf = (i2 >> 10) & 3;
    const int kk = (i2 >> 9) & 1;
    const int l  = (i2 >> 3) & 63;
    const int j  = i2 & 7;
    const int co = nf * 16 + (l & 15);
    const int ci = kk * 32 + ((l >> 4) << 3) + j;
    Wqb[i2] = __float2bfloat16(Wq[co * C_ + ci] * 0.3535533905932738f);
  } else if (i < 118784) {                            // Wo
    const int i3 = i - 114688;
    const int nf = (i3 >> 10) & 3;
    const int kk = (i3 >> 9) & 1;
    const int l  = (i3 >> 3) & 63;
    const int j  = i3 & 7;
    const int co = nf * 16 + (l & 15);
    const int ci = kk * 32 + ((l >> 4) << 3) + j;
    Wob[i3] = __float2bfloat16(Wo[co * C_ + ci]);
  } else if (i < 135168) {                            // Wk / Wv B-frags
    const int i4 = (i - 118784) & 8191;
    const bool is_v = (i - 118784) >= 8192;
    const int ch = i4 >> 12;
    const int kk = (i4 >> 9) & 7;
    const int l  = (i4 >> 3) & 63;
    const int j  = i4 & 7;
    const int c  = ch * 32 + (l & 31);
    const int e  = kk * 16 + ((l >> 5) << 3) + j;
    const float v = (is_v ? Wv : Wk)[c * EMB_ + e];
    (is_v ? Wvb : Wkb)[i4] = __float2bfloat16(v);
  }
}

// ---------------------------------------------------------------------------
// Kernel 1: K/V projection + attn fragment-buffer emission (unchanged).
// ---------------------------------------------------------------------------
__global__ __launch_bounds__(256) void kv_kernel(
    const float* __restrict__ mol,
    const __hip_bfloat16* __restrict__ Wkb, const float* __restrict__ bk,
    const __hip_bfloat16* __restrict__ Wvb, const float* __restrict__ bv,
    unsigned short* __restrict__ kfb, unsigned short* __restrict__ vfb) {
  __shared__ float smol[NATOM][132];
  __shared__ float res[2][NATOM][68];

  const int b    = blockIdx.x;
  const int tid  = threadIdx.x;
  const int lane = tid & 63;
  const int w    = tid >> 6;
  const int kvw  = w >> 1;
  const int ah   = w & 1;

  for (int i = tid; i < 2048; i += 256) {
    const int a = i >> 4, cb = (i & 15) * 8;
    const f32x4 v0 = *(const f32x4*)&mol[(size_t)(b * NATOM + a) * EMB_ + cb];
    const f32x4 v1 = *(const f32x4*)&mol[(size_t)(b * NATOM + a) * EMB_ + cb + 4];
    *(f32x4*)&smol[a][cb]     = v0;
    *(f32x4*)&smol[a][cb + 4] = v1;
  }
  __syncthreads();

  const __hip_bfloat16* Wb   = kvw ? Wvb : Wkb;
  const float*          bias = kvw ? bv : bk;

  f32x16 acc[2];
  #pragma unroll
  for (int ch = 0; ch < 2; ++ch)
    #pragma unroll
    for (int r = 0; r < 16; ++r) acc[ch][r] = 0.f;

  const int a = ah * 32 + (lane & 31);
  #pragma unroll
  for (int kk = 0; kk < 8; ++kk) {
    const int e0 = kk * 16 + ((lane >> 5) << 3);
    ushort8 au;
    #pragma unroll
    for (int j = 0; j < 8; ++j) au[j] = bf16u(smol[a][e0 + j]);
    const bf16x8 af = __builtin_bit_cast(bf16x8, au);
    #pragma unroll
    for (int ch = 0; ch < 2; ++ch) {
      const bf16x8 bf = *(const bf16x8*)(Wb + (((ch * 8 + kk) << 6) + lane) * 8);
      acc[ch] = __builtin_amdgcn_mfma_f32_32x32x16_bf16(af, bf, acc[ch], 0, 0, 0);
    }
  }

  #pragma unroll
  for (int ch = 0; ch < 2; ++ch) {
    const int c = ch * 32 + (lane & 31);
    const float bb = bias[c];
    #pragma unroll
    for (int r = 0; r < 16; ++r) {
      const int ar = ah * 32 + (r & 3) + 8 * (r >> 2) + 4 * (lane >> 5);
      res[kvw][ar][c] = acc[ch][r] + bb;
    }
  }
  __syncthreads();

  #pragma unroll
  for (int t = 0; t < 8; ++t) {
    const int idx = t * 256 + tid;
    const int h = idx >> 8, aa = (idx >> 6) & 3, ln = idx & 63;
    const int qd = ln >> 4, l15 = ln & 15;
    ushort8 au;
    if (qd == 0) {
      #pragma unroll
      for (int j = 0; j < 8; ++j) au[j] = bf16u(res[0][aa * 16 + l15][h * 8 + j]);
    } else {
      #pragma unroll
      for (int j = 0; j < 8; ++j) au[j] = 0;
    }
    *(ushort8*)(kfb + (size_t)(((b * 8 + h) * 4 + aa) * 64 + ln) * 8) = au;
  }
  #pragma unroll
  for (int t = 0; t < 4; ++t) {
    const int idx = t * 256 + tid;
    const int h = idx >> 7, s = (idx >> 6) & 1, ln = idx & 63;
    const int qd = ln >> 4, l15 = ln & 15;
    ushort8 au;
    #pragma unroll
    for (int j = 0; j < 8; ++j) {
      const int atom = (2 * s + (j >> 2)) * 16 + qd * 4 + (j & 3);
      au[j] = bf16u(res[1][atom][h * 8 + (l15 & 7)]);
    }
    *(ushort8*)(vfb + (size_t)(((b * 8 + h) * 2 + s) * 64 + ln) * 8) = au;
  }
}

// ---------------------------------------------------------------------------
// Kernel 2: fully-MFMA fused attention, fragment-fed.
// R16: ragged tile-skip — nv is block-uniform; atom-tiles >= natile are
// skipped in QK^T, softmax VALU, and PV (their P is exactly 0, matching the
// old exp(-1e30)=0 math bit-for-bit). Mean nv~32 -> ~half the attn core.
// ---------------------------------------------------------------------------
__global__ __launch_bounds__(512, 4) void attn_kernel(
    const float* __restrict__ x,
    const unsigned short* __restrict__ kfb, const unsigned short* __restrict__ vfb,
    const int* __restrict__ batch_nodes,
    const __hip_bfloat16* __restrict__ Wqb, const float* __restrict__ bq,
    const __hip_bfloat16* __restrict__ Wob, const float* __restrict__ bo,
    __hip_bfloat16* __restrict__ omid) {
  __shared__ float buf[64 * C_];     // 16 KB, multi-phase

  const int b    = blockIdx.y;
  const int m0   = blockIdx.x * 64;
  const int tid  = threadIdx.x;
  const int lane = tid & 63;
  const int w    = __builtin_amdgcn_readfirstlane(tid >> 6);   // 0..7
  const int h    = w;
  const int quad = lane >> 4;
  const int l15  = lane & 15;
  const int vq   = w & 3;
  const int cq   = w >> 2;

  bf16x8 kf[4], vf[2];
  #pragma unroll
  for (int a = 0; a < 4; ++a)
    kf[a] = __builtin_bit_cast(bf16x8,
        *(const ushort8*)(kfb + (size_t)(((b * 8 + h) * 4 + a) * 64 + lane) * 8));
  #pragma unroll
  for (int s = 0; s < 2; ++s)
    vf[s] = __builtin_bit_cast(bf16x8,
        *(const ushort8*)(vfb + (size_t)(((b * 8 + h) * 2 + s) * 64 + lane) * 8));

  #pragma unroll
  for (int j = 0; j < 2; ++j) {
    const int cidx = w * 2 + j;
    const int c  = cidx * 4 + (lane >> 4);
    const int v4 = (lane & 15) * 4;
    const float* gsrc = x + (size_t)(b * C_ + c) * MVOX + m0 + v4;
    __builtin_amdgcn_global_load_lds((gas_u32*)gsrc,
                                     (las_u32*)&buf[cidx * 256], 16, 0, 0);
  }
  __syncthreads();

  f32x4 qacc[2];
  {
    bf16x8 af[2];
    #pragma unroll
    for (int kk = 0; kk < 2; ++kk) {
      ushort8 au;
      #pragma unroll
      for (int j = 0; j < 8; ++j)
        au[j] = bf16u(buf[(kk * 32 + quad * 8 + j) * 64 + vq * 16 + l15]);
      af[kk] = __builtin_bit_cast(bf16x8, au);
    }
    #pragma unroll
    for (int nf2 = 0; nf2 < 2; ++nf2) {
      const int nf = cq * 2 + nf2;
      const float bqv = bq[nf * 16 + l15] * 0.3535533905932738f;
      qacc[nf2] = {bqv, bqv, bqv, bqv};
      #pragma unroll
      for (int kk = 0; kk < 2; ++kk) {
        const bf16x8 bf = *(const bf16x8*)(Wqb + (((nf * 2 + kk) << 6) + lane) * 8);
        qacc[nf2] = __builtin_amdgcn_mfma_f32_16x16x32_bf16(af[kk], bf, qacc[nf2], 0, 0, 0);
      }
    }
  }
  __syncthreads();

  unsigned short* qb = (unsigned short*)buf;
  #pragma unroll
  for (int nf2 = 0; nf2 < 2; ++nf2) {
    const int co = (cq * 2 + nf2) * 16 + l15;
    #pragma unroll
    for (int r = 0; r < 4; ++r) {
      const int vr = vq * 16 + quad * 4 + r;
      qb[vr * 64 + (((co >> 3) ^ (vr & 7)) << 3) + (co & 7)] = bf16u(qacc[nf2][r]);
    }
  }
  __syncthreads();

  const int nv     = batch_nodes[b];        // uniform 1..64
  const int natile = (nv + 15) >> 4;        // live 16-atom tiles: 1..4
  unsigned short* ob = (unsigned short*)buf + 4096;

  f32x4 oacc[4];
  #pragma unroll
  for (int v = 0; v < 4; ++v)
    #pragma unroll
    for (int r = 0; r < 4; ++r) oacc[v][r] = 0.f;

  const f32x4 zero4 = {0.f, 0.f, 0.f, 0.f};
  #pragma unroll
  for (int v = 0; v < 4; ++v) {
    const int qrow = v * 16 + l15;
    const bf16x8 qf = __builtin_bit_cast(bf16x8,
        *(const ushort8*)&qb[qrow * 64 + ((h ^ (qrow & 7)) << 3)]);

    f32x4 st[4];
    #pragma unroll
    for (int a = 0; a < 4; ++a) {
      if (a < natile)      // uniform branch: dead tiles skipped
        st[a] = __builtin_amdgcn_mfma_f32_16x16x32_bf16(kf[a], qf, zero4, 0, 0, 0);
      else
        st[a] = zero4;
    }

    float m = -1e30f;
    #pragma unroll
    for (int a = 0; a < 4; ++a)
      if (a < natile) {
        #pragma unroll
        for (int r = 0; r < 4; ++r) {
          const int atom = a * 16 + quad * 4 + r;
          const float val = (atom < nv) ? st[a][r] : -1e30f;
          st[a][r] = val;
          m = fmaxf(m, val);
        }
      }
    m = fmaxf(m, __shfl_xor(m, 16, 64));
    m = fmaxf(m, __shfl_xor(m, 32, 64));
    float ssum = 0.f;
    #pragma unroll
    for (int a = 0; a < 4; ++a)
      if (a < natile) {
        #pragma unroll
        for (int r = 0; r < 4; ++r) {
          const float p = __expf(st[a][r] - m);
          st[a][r] = p;
          ssum += p;
        }
      }
    ssum += __shfl_xor(ssum, 16, 64);
    ssum += __shfl_xor(ssum, 32, 64);
    const float inv = 1.f / ssum;

    #pragma unroll
    for (int s = 0; s < 2; ++s) {
      if (s * 32 < nv) {   // uniform: skip PV when both source tiles dead
        ushort8 pu;
        #pragma unroll
        for (int j = 0; j < 8; ++j) {
          const int tile = 2 * s + (j >> 2);
          pu[j] = (tile < natile) ? bf16u(st[tile][j & 3] * inv)
                                  : (unsigned short)0;
        }
        const bf16x8 pa = __builtin_bit_cast(bf16x8, pu);
        oacc[v] = __builtin_amdgcn_mfma_f32_16x16x32_bf16(pa, vf[s], oacc[v], 0, 0, 0);
      }
    }
  }

  if (l15 < 8) {
    #pragma unroll
    for (int v = 0; v < 4; ++v)
      #pragma unroll
      for (int r = 0; r < 4; ++r) {
        const int vxr = v * 16 + quad * 4 + r;
        ob[vxr * 64 + ((h ^ (vxr & 7)) << 3) + l15] = bf16u(oacc[v][r]);
      }
  }
  __syncthreads();

  {
    bf16x8 af[2];
    #pragma unroll
    for (int kk = 0; kk < 2; ++kk) {
      const int row = vq * 16 + l15;
      af[kk] = __builtin_bit_cast(bf16x8,
          *(const ushort8*)&ob[row * 64 + (((kk * 4 + quad) ^ (row & 7)) << 3)]);
    }
    f32x4 oac[2];
    #pragma unroll
    for (int nf2 = 0; nf2 < 2; ++nf2) {
      const int nf = cq * 2 + nf2;
      const float bov = bo[nf * 16 + l15];
      oac[nf2] = {bov, bov, bov, bov};
      #pragma unroll
      for (int kk = 0; kk < 2; ++kk) {
        const bf16x8 bf = *(const bf16x8*)(Wob + (((nf * 2 + kk) << 6) + lane) * 8);
        oac[nf2] = __builtin_amdgcn_mfma_f32_16x16x32_bf16(af[kk], bf, oac[nf2], 0, 0, 0);
      }
    }
    __syncthreads();
    unsigned short* osb = (unsigned short*)buf;
    #pragma unroll
    for (int nf2 = 0; nf2 < 2; ++nf2) {
      const int co = (cq * 2 + nf2) * 16 + l15;
      #pragma unroll
      for (int r = 0; r < 4; ++r) {
        const int vr = vq * 16 + quad * 4 + r;
        osb[vr * 64 + (((co >> 3) ^ (vr & 7)) << 3) + (co & 7)] =
            bf16u(fmaxf(oac[nf2][r], 0.f));
      }
    }
  }
  __syncthreads();

  *(ushort8*)(omid + (size_t)(b * MVOX + m0) * C_ + tid * 8) =
      *(const ushort8*)&((unsigned short*)buf)[tid * 8];
}

// ---------------------------------------------------------------------------
// Kernel 3: conv3d 3x3x3 circular, implicit-GEMM mfma_f32_32x32x16_bf16.
// R16: W-amortized wave tile. Block = 4x4 lines (512 thr, 8 waves), halo
// 6x6 lines = 144 KB, grid = 64x4 = 256 blocks = EXACTLY 1/CU (no serial
// block rounds). Wave = (lg = x-line 0..3, coh): 4 y-lines x 32 co; per tap
// 16 B-reads + 4 W-loads + 16 MFMA -> W-L2 per output HALVED vs R11 while
// keeping 2 waves/SIMD (the R15 lesson) and same LDS traffic per line.
// ---------------------------------------------------------------------------
#define LOADB(dst, DX, DY, DZ)                                              \
  {                                                                         \
    const int zp_ = ((lane & 31) + (DZ) + 31) & 31;                         \
    const int sw_ = zp_ & 7;                                                \
    _Pragma("unroll")                                                       \
    for (int ks_ = 0; ks_ < 4; ++ks_) {                                     \
      const int phys_ = (ks_ * 2 + (lane >> 5)) ^ sw_;                      \
      _Pragma("unroll")                                                     \
      for (int ly_ = 0; ly_ < 4; ++ly_) {                                   \
        const int hl_ = (lg + (DX)) * 6 + (ly_ + (DY));                     \
        (dst)[ly_ * 4 + ks_] =                                              \
            *(const bf16x8*)&halo[((hl_ * 32 + zp_) * 8 + phys_) * 8];      \
      }                                                                     \
    }                                                                       \
  }

#define LOADW(T2)                                                           \
  _Pragma("unroll")                                                         \
  for (int ks_ = 0; ks_ < 4; ++ks_)                                         \
    wf[(T2) & 1][ks_] =                                                     \
        *(const bf16x8*)(Wt4 + ((((T2) * 2 + coh) * 4 + ks_) << 9) + lane * 8);

#define DOMFMA(src, T)                                                      \
  _Pragma("unroll")                                                         \
  for (int ks_ = 0; ks_ < 4; ++ks_)                                         \
    _Pragma("unroll")                                                       \
    for (int ly_ = 0; ly_ < 4; ++ly_)                                       \
      acc[ly_] = __builtin_amdgcn_mfma_f32_32x32x16_bf16(                   \
          wf[(T) & 1][ks_], (src)[ly_ * 4 + ks_], acc[ly_], 0, 0, 0);

__global__ __launch_bounds__(512, 2) void conv_kernel(
    const __hip_bfloat16* __restrict__ omid,
    const __hip_bfloat16* __restrict__ Wt4,
    const float* __restrict__ bc,
    const float* __restrict__ xin,
    float* __restrict__ out) {
  __shared__ __hip_bfloat16 halo[36 * 32 * 64];   // 144 KB: 6x6 lines

  const int b    = blockIdx.y;
  const int x0   = (blockIdx.x >> 3) * 4;
  const int y0   = (blockIdx.x & 7) * 4;
  const int tid  = threadIdx.x;
  const int lane = tid & 63;
  const int w    = tid >> 6;          // 0..7
  const int coh  = w & 1;             // co half
  const int lg   = w >> 1;            // x-line 0..3

  // --- halo staging: 144 chunks x 1KB, wave w stages 18 ---
  {
    const __hip_bfloat16* src = omid + (size_t)b * MVOX * C_;
    #pragma unroll
    for (int n = 0; n < 18; ++n) {
      const int chunk = w * 18 + n;               // 0..143
      const int li = chunk >> 2;                  // halo line 0..35
      const int zb = (chunk & 3) * 8;
      const int hx = li / 6, hy = li % 6;
      const int gx = (x0 - 1 + hx) & 31;
      const int gy = (y0 - 1 + hy) & 31;
      const __hip_bfloat16* gsrc = src + (size_t)(gx * 1024 + gy * 32 + zb) * C_ + lane * 8;
      __builtin_amdgcn_global_load_lds((gas_u32*)gsrc,
                                       (las_u32*)&halo[chunk * 512], 16, 0, 0);
    }
  }

  // --- weight ring (2 slots): tap 0 prefetched ---
  bf16x8 wf[2][4];
  LOADW(0);
  __syncthreads();   // halo staged

  f32x16 acc[4];     // 4 y-lines x (32 co x 32 z)
  #pragma unroll
  for (int ly = 0; ly < 4; ++ly)
    #pragma unroll
    for (int r = 0; r < 16; ++r) acc[ly][r] = 0.f;

  // --- B double buffer: 16 frags per tap, 1-tap lookahead ---
  bf16x8 bA[16], bB[16];
  LOADB(bA, 0, 0, 0);   // tap 0

  #pragma unroll
  for (int t = 0; t < 27; ++t) {
    const int tn = t + 1;
    if (tn < 27) {
      if ((t & 1) == 0) LOADB(bB, tn / 9, (tn / 3) % 3, tn % 3)
      else              LOADB(bA, tn / 9, (tn / 3) % 3, tn % 3)
      LOADW(tn);
    }
    if ((t & 1) == 0) DOMFMA(bA, t)
    else              DOMFMA(bB, t)
  }

  // --- epilogue: relu(acc+bias) + residual; wave writes 4 lines x 32 co ---
  const int z = lane & 31;
  const int gx = x0 + lg;
  #pragma unroll
  for (int ly = 0; ly < 4; ++ly) {
    const int gy = y0 + ly;
    #pragma unroll
    for (int r = 0; r < 16; ++r) {
      const int co = coh * 32 + (r & 3) + 8 * (r >> 2) + 4 * (lane >> 5);
      const size_t idx = ((size_t)(b * C_ + co)) * MVOX + gx * 1024 + gy * 32 + z;
      out[idx] = fmaxf(acc[ly][r] + bc[co], 0.f) + xin[idx];
    }
  }
}

// ---------------------------------------------------------------------------
extern "C" void kernel_launch(void* const* d_in, const int* in_sizes, int n_in,
                              void* d_out, int out_size, void* d_ws, size_t ws_size,
                              hipStream_t stream) {
  const float* x   = (const float*)d_in[0];
  const float* mol = (const float*)d_in[1];
  const int*   bn  = (const int*)  d_in[2];
  const float* Wq  = (const float*)d_in[3];
  const float* bq  = (const float*)d_in[4];
  const float* Wk  = (const float*)d_in[5];
  const float* bk  = (const float*)d_in[6];
  const float* Wv  = (const float*)d_in[7];
  const float* bv  = (const float*)d_in[8];
  const float* Wo  = (const float*)d_in[9];
  const float* bo  = (const float*)d_in[10];
  const float* Wc  = (const float*)d_in[11];
  const float* bc  = (const float*)d_in[12];
  float* out = (float*)d_out;

  char* ws = (char*)d_ws;
  __hip_bfloat16* omid = (__hip_bfloat16*)ws;                     // 16,777,216 B
  __hip_bfloat16* Wt4  = (__hip_bfloat16*)(ws + 16777216);        // 221,184 B
  __hip_bfloat16* Wqb  = (__hip_bfloat16*)(ws + 16998400);        // 8,192 B
  __hip_bfloat16* Wob  = (__hip_bfloat16*)(ws + 17006592);        // 8,192 B
  __hip_bfloat16* Wkb  = (__hip_bfloat16*)(ws + 17014784);        // 16,384 B
  __hip_bfloat16* Wvb  = (__hip_bfloat16*)(ws + 17031168);        // 16,384 B
  unsigned short* kfb  = (unsigned short*)(ws + 17047552);        // 131,072 B
  unsigned short* vfb  = (unsigned short*)(ws + 17178624);        // 65,536 B

  wprep_kernel<<<dim3(528), 256, 0, stream>>>(Wc, Wq, Wo, Wk, Wv,
                                              Wt4, Wqb, Wob, Wkb, Wvb);
  kv_kernel<<<dim3(B_), 256, 0, stream>>>(mol, Wkb, bk, Wvb, bv, kfb, vfb);
  attn_kernel<<<dim3(MVOX / 64, B_), 512, 0, stream>>>(x, kfb, vfb, bn, Wqb, bq, Wob, bo, omid);
  conv_kernel<<<dim3(64, B_), 512, 0, stream>>>(omid, Wt4, bc, x, out);
}

// Round 17
// 87.086 us; speedup vs baseline: 1.3024x; 1.0398x over previous
//
#include <hip/hip_runtime.h>
#include <hip/hip_bf16.h>

#define B_    4
#define C_    64
#define MVOX  32768      // 32*32*32
#define NATOM 64
#define EMB_  128

typedef __attribute__((ext_vector_type(8)))  __bf16 bf16x8;
typedef __attribute__((ext_vector_type(4)))  float  f32x4;
typedef __attribute__((ext_vector_type(16))) float  f32x16;
typedef __attribute__((ext_vector_type(8)))  unsigned short ushort8;

typedef __attribute__((address_space(1))) const unsigned int gas_u32;
typedef __attribute__((address_space(3))) unsigned int las_u32;

static __device__ __forceinline__ unsigned short bf16u(float f) {
  __hip_bfloat16 h = __float2bfloat16(f);
  return *(unsigned short*)&h;
}

// ---------------------------------------------------------------------------
// Kernel 0: weight prep (unchanged).
// ---------------------------------------------------------------------------
__global__ __launch_bounds__(256) void wprep_kernel(
    const float* __restrict__ Wc, const float* __restrict__ Wq,
    const float* __restrict__ Wo, const float* __restrict__ Wk,
    const float* __restrict__ Wv,
    __hip_bfloat16* __restrict__ Wt4, __hip_bfloat16* __restrict__ Wqb,
    __hip_bfloat16* __restrict__ Wob, __hip_bfloat16* __restrict__ Wkb,
    __hip_bfloat16* __restrict__ Wvb) {
  const int i = blockIdx.x * 256 + threadIdx.x;
  if (i < 110592) {                                   // conv weights
    const int tap = i >> 12;
    const int coh = (i >> 11) & 1;
    const int ks  = (i >> 9) & 3;
    const int l   = (i >> 3) & 63;
    const int j   = i & 7;
    const int co  = coh * 32 + (l & 31);
    const int ci  = ks * 16 + ((l >> 5) << 3) + j;
    Wt4[i] = __float2bfloat16(Wc[(co * C_ + ci) * 27 + tap]);
  } else if (i < 114688) {                            // Wq (scaled)
    const int i2 = i - 110592;
    const int nf = (i2 >> 10) & 3;
    const int kk = (i2 >> 9) & 1;
    const int l  = (i2 >> 3) & 63;
    const int j  = i2 & 7;
    const int co = nf * 16 + (l & 15);
    const int ci = kk * 32 + ((l >> 4) << 3) + j;
    Wqb[i2] = __float2bfloat16(Wq[co * C_ + ci] * 0.3535533905932738f);
  } else if (i < 118784) {                            // Wo
    const int i3 = i - 114688;
    const int nf = (i3 >> 10) & 3;
    const int kk = (i3 >> 9) & 1;
    const int l  = (i3 >> 3) & 63;
    const int j  = i3 & 7;
    const int co = nf * 16 + (l & 15);
    const int ci = kk * 32 + ((l >> 4) << 3) + j;
    Wob[i3] = __float2bfloat16(Wo[co * C_ + ci]);
  } else if (i < 135168) {                            // Wk / Wv B-frags
    const int i4 = (i - 118784) & 8191;
    const bool is_v = (i - 118784) >= 8192;
    const int ch = i4 >> 12;
    const int kk = (i4 >> 9) & 7;
    const int l  = (i4 >> 3) & 63;
    const int j  = i4 & 7;
    const int c  = ch * 32 + (l & 31);
    const int e  = kk * 16 + ((l >> 5) << 3) + j;
    const float v = (is_v ? Wv : Wk)[c * EMB_ + e];
    (is_v ? Wvb : Wkb)[i4] = __float2bfloat16(v);
  }
}

// ---------------------------------------------------------------------------
// Kernel 1: K/V projection + attn fragment-buffer emission (unchanged).
// ---------------------------------------------------------------------------
__global__ __launch_bounds__(256) void kv_kernel(
    const float* __restrict__ mol,
    const __hip_bfloat16* __restrict__ Wkb, const float* __restrict__ bk,
    const __hip_bfloat16* __restrict__ Wvb, const float* __restrict__ bv,
    unsigned short* __restrict__ kfb, unsigned short* __restrict__ vfb) {
  __shared__ float smol[NATOM][132];
  __shared__ float res[2][NATOM][68];

  const int b    = blockIdx.x;
  const int tid  = threadIdx.x;
  const int lane = tid & 63;
  const int w    = tid >> 6;
  const int kvw  = w >> 1;
  const int ah   = w & 1;

  for (int i = tid; i < 2048; i += 256) {
    const int a = i >> 4, cb = (i & 15) * 8;
    const f32x4 v0 = *(const f32x4*)&mol[(size_t)(b * NATOM + a) * EMB_ + cb];
    const f32x4 v1 = *(const f32x4*)&mol[(size_t)(b * NATOM + a) * EMB_ + cb + 4];
    *(f32x4*)&smol[a][cb]     = v0;
    *(f32x4*)&smol[a][cb + 4] = v1;
  }
  __syncthreads();

  const __hip_bfloat16* Wb   = kvw ? Wvb : Wkb;
  const float*          bias = kvw ? bv : bk;

  f32x16 acc[2];
  #pragma unroll
  for (int ch = 0; ch < 2; ++ch)
    #pragma unroll
    for (int r = 0; r < 16; ++r) acc[ch][r] = 0.f;

  const int a = ah * 32 + (lane & 31);
  #pragma unroll
  for (int kk = 0; kk < 8; ++kk) {
    const int e0 = kk * 16 + ((lane >> 5) << 3);
    ushort8 au;
    #pragma unroll
    for (int j = 0; j < 8; ++j) au[j] = bf16u(smol[a][e0 + j]);
    const bf16x8 af = __builtin_bit_cast(bf16x8, au);
    #pragma unroll
    for (int ch = 0; ch < 2; ++ch) {
      const bf16x8 bf = *(const bf16x8*)(Wb + (((ch * 8 + kk) << 6) + lane) * 8);
      acc[ch] = __builtin_amdgcn_mfma_f32_32x32x16_bf16(af, bf, acc[ch], 0, 0, 0);
    }
  }

  #pragma unroll
  for (int ch = 0; ch < 2; ++ch) {
    const int c = ch * 32 + (lane & 31);
    const float bb = bias[c];
    #pragma unroll
    for (int r = 0; r < 16; ++r) {
      const int ar = ah * 32 + (r & 3) + 8 * (r >> 2) + 4 * (lane >> 5);
      res[kvw][ar][c] = acc[ch][r] + bb;
    }
  }
  __syncthreads();

  #pragma unroll
  for (int t = 0; t < 8; ++t) {
    const int idx = t * 256 + tid;
    const int h = idx >> 8, aa = (idx >> 6) & 3, ln = idx & 63;
    const int qd = ln >> 4, l15 = ln & 15;
    ushort8 au;
    if (qd == 0) {
      #pragma unroll
      for (int j = 0; j < 8; ++j) au[j] = bf16u(res[0][aa * 16 + l15][h * 8 + j]);
    } else {
      #pragma unroll
      for (int j = 0; j < 8; ++j) au[j] = 0;
    }
    *(ushort8*)(kfb + (size_t)(((b * 8 + h) * 4 + aa) * 64 + ln) * 8) = au;
  }
  #pragma unroll
  for (int t = 0; t < 4; ++t) {
    const int idx = t * 256 + tid;
    const int h = idx >> 7, s = (idx >> 6) & 1, ln = idx & 63;
    const int qd = ln >> 4, l15 = ln & 15;
    ushort8 au;
    #pragma unroll
    for (int j = 0; j < 8; ++j) {
      const int atom = (2 * s + (j >> 2)) * 16 + qd * 4 + (j & 3);
      au[j] = bf16u(res[1][atom][h * 8 + (l15 & 7)]);
    }
    *(ushort8*)(vfb + (size_t)(((b * 8 + h) * 2 + s) * 64 + ln) * 8) = au;
  }
}

// ---------------------------------------------------------------------------
// Kernel 2: fully-MFMA fused attention, fragment-fed (R14 version — the
// R16 tile-skip branches regressed it and are reverted).
// ---------------------------------------------------------------------------
__global__ __launch_bounds__(512, 4) void attn_kernel(
    const float* __restrict__ x,
    const unsigned short* __restrict__ kfb, const unsigned short* __restrict__ vfb,
    const int* __restrict__ batch_nodes,
    const __hip_bfloat16* __restrict__ Wqb, const float* __restrict__ bq,
    const __hip_bfloat16* __restrict__ Wob, const float* __restrict__ bo,
    __hip_bfloat16* __restrict__ omid) {
  __shared__ float buf[64 * C_];     // 16 KB, multi-phase

  const int b    = blockIdx.y;
  const int m0   = blockIdx.x * 64;
  const int tid  = threadIdx.x;
  const int lane = tid & 63;
  const int w    = __builtin_amdgcn_readfirstlane(tid >> 6);   // 0..7
  const int h    = w;
  const int quad = lane >> 4;
  const int l15  = lane & 15;
  const int vq   = w & 3;
  const int cq   = w >> 2;

  bf16x8 kf[4], vf[2];
  #pragma unroll
  for (int a = 0; a < 4; ++a)
    kf[a] = __builtin_bit_cast(bf16x8,
        *(const ushort8*)(kfb + (size_t)(((b * 8 + h) * 4 + a) * 64 + lane) * 8));
  #pragma unroll
  for (int s = 0; s < 2; ++s)
    vf[s] = __builtin_bit_cast(bf16x8,
        *(const ushort8*)(vfb + (size_t)(((b * 8 + h) * 2 + s) * 64 + lane) * 8));

  #pragma unroll
  for (int j = 0; j < 2; ++j) {
    const int cidx = w * 2 + j;
    const int c  = cidx * 4 + (lane >> 4);
    const int v4 = (lane & 15) * 4;
    const float* gsrc = x + (size_t)(b * C_ + c) * MVOX + m0 + v4;
    __builtin_amdgcn_global_load_lds((gas_u32*)gsrc,
                                     (las_u32*)&buf[cidx * 256], 16, 0, 0);
  }
  __syncthreads();

  f32x4 qacc[2];
  {
    bf16x8 af[2];
    #pragma unroll
    for (int kk = 0; kk < 2; ++kk) {
      ushort8 au;
      #pragma unroll
      for (int j = 0; j < 8; ++j)
        au[j] = bf16u(buf[(kk * 32 + quad * 8 + j) * 64 + vq * 16 + l15]);
      af[kk] = __builtin_bit_cast(bf16x8, au);
    }
    #pragma unroll
    for (int nf2 = 0; nf2 < 2; ++nf2) {
      const int nf = cq * 2 + nf2;
      const float bqv = bq[nf * 16 + l15] * 0.3535533905932738f;
      qacc[nf2] = {bqv, bqv, bqv, bqv};
      #pragma unroll
      for (int kk = 0; kk < 2; ++kk) {
        const bf16x8 bf = *(const bf16x8*)(Wqb + (((nf * 2 + kk) << 6) + lane) * 8);
        qacc[nf2] = __builtin_amdgcn_mfma_f32_16x16x32_bf16(af[kk], bf, qacc[nf2], 0, 0, 0);
      }
    }
  }
  __syncthreads();

  unsigned short* qb = (unsigned short*)buf;
  #pragma unroll
  for (int nf2 = 0; nf2 < 2; ++nf2) {
    const int co = (cq * 2 + nf2) * 16 + l15;
    #pragma unroll
    for (int r = 0; r < 4; ++r) {
      const int vr = vq * 16 + quad * 4 + r;
      qb[vr * 64 + (((co >> 3) ^ (vr & 7)) << 3) + (co & 7)] = bf16u(qacc[nf2][r]);
    }
  }
  __syncthreads();

  const int nv = batch_nodes[b];
  unsigned short* ob = (unsigned short*)buf + 4096;

  f32x4 oacc[4];
  #pragma unroll
  for (int v = 0; v < 4; ++v)
    #pragma unroll
    for (int r = 0; r < 4; ++r) oacc[v][r] = 0.f;

  const f32x4 zero4 = {0.f, 0.f, 0.f, 0.f};
  #pragma unroll
  for (int v = 0; v < 4; ++v) {
    const int qrow = v * 16 + l15;
    const bf16x8 qf = __builtin_bit_cast(bf16x8,
        *(const ushort8*)&qb[qrow * 64 + ((h ^ (qrow & 7)) << 3)]);

    f32x4 st[4];
    #pragma unroll
    for (int a = 0; a < 4; ++a)
      st[a] = __builtin_amdgcn_mfma_f32_16x16x32_bf16(kf[a], qf, zero4, 0, 0, 0);

    float m = -1e30f;
    #pragma unroll
    for (int a = 0; a < 4; ++a)
      #pragma unroll
      for (int r = 0; r < 4; ++r) {
        const int atom = a * 16 + quad * 4 + r;
        const float val = (atom < nv) ? st[a][r] : -1e30f;
        st[a][r] = val;
        m = fmaxf(m, val);
      }
    m = fmaxf(m, __shfl_xor(m, 16, 64));
    m = fmaxf(m, __shfl_xor(m, 32, 64));
    float ssum = 0.f;
    #pragma unroll
    for (int a = 0; a < 4; ++a)
      #pragma unroll
      for (int r = 0; r < 4; ++r) {
        const float p = __expf(st[a][r] - m);
        st[a][r] = p;
        ssum += p;
      }
    ssum += __shfl_xor(ssum, 16, 64);
    ssum += __shfl_xor(ssum, 32, 64);
    const float inv = 1.f / ssum;

    #pragma unroll
    for (int s = 0; s < 2; ++s) {
      ushort8 pu;
      #pragma unroll
      for (int j = 0; j < 8; ++j)
        pu[j] = bf16u(st[2 * s + (j >> 2)][j & 3] * inv);
      const bf16x8 pa = __builtin_bit_cast(bf16x8, pu);
      oacc[v] = __builtin_amdgcn_mfma_f32_16x16x32_bf16(pa, vf[s], oacc[v], 0, 0, 0);
    }
  }

  if (l15 < 8) {
    #pragma unroll
    for (int v = 0; v < 4; ++v)
      #pragma unroll
      for (int r = 0; r < 4; ++r) {
        const int vxr = v * 16 + quad * 4 + r;
        ob[vxr * 64 + ((h ^ (vxr & 7)) << 3) + l15] = bf16u(oacc[v][r]);
      }
  }
  __syncthreads();

  {
    bf16x8 af[2];
    #pragma unroll
    for (int kk = 0; kk < 2; ++kk) {
      const int row = vq * 16 + l15;
      af[kk] = __builtin_bit_cast(bf16x8,
          *(const ushort8*)&ob[row * 64 + (((kk * 4 + quad) ^ (row & 7)) << 3)]);
    }
    f32x4 oac[2];
    #pragma unroll
    for (int nf2 = 0; nf2 < 2; ++nf2) {
      const int nf = cq * 2 + nf2;
      const float bov = bo[nf * 16 + l15];
      oac[nf2] = {bov, bov, bov, bov};
      #pragma unroll
      for (int kk = 0; kk < 2; ++kk) {
        const bf16x8 bf = *(const bf16x8*)(Wob + (((nf * 2 + kk) << 6) + lane) * 8);
        oac[nf2] = __builtin_amdgcn_mfma_f32_16x16x32_bf16(af[kk], bf, oac[nf2], 0, 0, 0);
      }
    }
    __syncthreads();
    unsigned short* osb = (unsigned short*)buf;
    #pragma unroll
    for (int nf2 = 0; nf2 < 2; ++nf2) {
      const int co = (cq * 2 + nf2) * 16 + l15;
      #pragma unroll
      for (int r = 0; r < 4; ++r) {
        const int vr = vq * 16 + quad * 4 + r;
        osb[vr * 64 + (((co >> 3) ^ (vr & 7)) << 3) + (co & 7)] =
            bf16u(fmaxf(oac[nf2][r], 0.f));
      }
    }
  }
  __syncthreads();

  *(ushort8*)(omid + (size_t)(b * MVOX + m0) * C_ + tid * 8) =
      *(const ushort8*)&((unsigned short*)buf)[tid * 8];
}

// ---------------------------------------------------------------------------
// Kernel 3: conv3d 3x3x3 circular — R14 structure (best) with ONE change:
// the 32 xin residual values are prefetched into registers at kernel entry
// (loads issue alongside halo staging; the single barrier drains them).
// The epilogue's 33.5 MB xin read was a serial memory TAIL after all taps;
// now it overlaps staging+compute. Epilogue = relu+add+store only.
// ---------------------------------------------------------------------------
#define LOADB(dst, DX, DY, DZ)                                              \
  {                                                                         \
    const int zp_ = ((lane & 31) + (DZ) + 31) & 31;                         \
    const int sw_ = zp_ & 7;                                                \
    _Pragma("unroll")                                                       \
    for (int ks_ = 0; ks_ < 4; ++ks_) {                                     \
      const int phys_ = (ks_ * 2 + (lane >> 5)) ^ sw_;                      \
      _Pragma("unroll")                                                     \
      for (int i_ = 0; i_ < 2; ++i_) {                                      \
        const int hl_ = (lp + (DX)) * 4 + (i_ + (DY));                      \
        (dst)[i_ * 4 + ks_] =                                               \
            *(const bf16x8*)&halo[((hl_ * 32 + zp_) * 8 + phys_) * 8];      \
      }                                                                     \
    }                                                                       \
  }

#define LOADW(T2)                                                           \
  _Pragma("unroll")                                                         \
  for (int ks_ = 0; ks_ < 4; ++ks_)                                         \
    wf[(T2) % 3][ks_] =                                                     \
        *(const bf16x8*)(Wt4 + ((((T2) * 2 + coh) * 4 + ks_) << 9) + lane * 8);

#define DOMFMA(src, T)                                                      \
  _Pragma("unroll")                                                         \
  for (int ks_ = 0; ks_ < 4; ++ks_)                                         \
    _Pragma("unroll")                                                       \
    for (int i_ = 0; i_ < 2; ++i_)                                          \
      acc[i_] = __builtin_amdgcn_mfma_f32_32x32x16_bf16(                    \
          wf[(T) % 3][ks_], (src)[i_ * 4 + ks_], acc[i_], 0, 0, 0);

__global__ __launch_bounds__(256, 2) void conv_kernel(
    const __hip_bfloat16* __restrict__ omid,
    const __hip_bfloat16* __restrict__ Wt4,
    const float* __restrict__ bc,
    const float* __restrict__ xin,
    float* __restrict__ out) {
  __shared__ __hip_bfloat16 halo[512 * 64];   // 64 KB

  const int b    = blockIdx.y;
  const int x0   = (blockIdx.x >> 4) * 2;
  const int y0   = (blockIdx.x & 15) * 2;
  const int tid  = threadIdx.x;
  const int lane = tid & 63;
  const int w    = tid >> 6;
  const int coh  = w & 1;
  const int lp   = w >> 1;

  // --- xin residual prefetch: 32 coalesced 4B loads, consumed in epilogue ---
  float xr[2][16];
  {
    const int zl = lane & 31;
    #pragma unroll
    for (int i = 0; i < 2; ++i) {
      const int gx = x0 + lp, gy = y0 + i;
      #pragma unroll
      for (int r = 0; r < 16; ++r) {
        const int co = coh * 32 + (r & 3) + 8 * (r >> 2) + 4 * (lane >> 5);
        xr[i][r] = xin[((size_t)(b * C_ + co)) * MVOX + gx * 1024 + gy * 32 + zl];
      }
    }
  }

  // --- halo staging: 64 chunks x 1KB via global_load_lds ---
  {
    const __hip_bfloat16* src = omid + (size_t)b * MVOX * C_;
    #pragma unroll
    for (int n = 0; n < 16; ++n) {
      const int chunk = w * 16 + n;
      const int li = chunk >> 2;
      const int zb = (chunk & 3) * 8;
      const int gx = (x0 - 1 + (li >> 2)) & 31;
      const int gy = (y0 - 1 + (li & 3)) & 31;
      const __hip_bfloat16* gsrc = src + (size_t)(gx * 1024 + gy * 32 + zb) * C_ + lane * 8;
      __builtin_amdgcn_global_load_lds((gas_u32*)gsrc,
                                       (las_u32*)&halo[chunk * 512], 16, 0, 0);
    }
  }

  // --- weight register ring: taps 0,1 prefetched ---
  bf16x8 wf[3][4];
  LOADW(0);
  LOADW(1);
  __syncthreads();   // halo staged (xin loads also drained here)

  f32x16 acc[2];
  #pragma unroll
  for (int i = 0; i < 2; ++i)
    #pragma unroll
    for (int r = 0; r < 16; ++r) acc[i][r] = 0.f;

  // --- B-fragment ring: 3 buffers, 2 taps of lookahead ---
  bf16x8 bR[3][8];
  LOADB(bR[0], 0, 0, 0);   // tap 0
  LOADB(bR[1], 0, 0, 1);   // tap 1

  #pragma unroll
  for (int t = 0; t < 27; ++t) {
    const int tn = t + 2;
    if (tn < 27) {
      LOADB(bR[tn % 3], tn / 9, (tn / 3) % 3, tn % 3);
      LOADW(tn);
    }
    DOMFMA(bR[t % 3], t);
  }

  // --- epilogue: relu(acc+bias) + prefetched residual ---
  const int z = lane & 31;
  #pragma unroll
  for (int i = 0; i < 2; ++i) {
    const int gx = x0 + lp, gy = y0 + i;
    #pragma unroll
    for (int r = 0; r < 16; ++r) {
      const int co = coh * 32 + (r & 3) + 8 * (r >> 2) + 4 * (lane >> 5);
      const size_t idx = ((size_t)(b * C_ + co)) * MVOX + gx * 1024 + gy * 32 + z;
      out[idx] = fmaxf(acc[i][r] + bc[co], 0.f) + xr[i][r];
    }
  }
}

// ---------------------------------------------------------------------------
extern "C" void kernel_launch(void* const* d_in, const int* in_sizes, int n_in,
                              void* d_out, int out_size, void* d_ws, size_t ws_size,
                              hipStream_t stream) {
  const float* x   = (const float*)d_in[0];
  const float* mol = (const float*)d_in[1];
  const int*   bn  = (const int*)  d_in[2];
  const float* Wq  = (const float*)d_in[3];
  const float* bq  = (const float*)d_in[4];
  const float* Wk  = (const float*)d_in[5];
  const float* bk  = (const float*)d_in[6];
  const float* Wv  = (const float*)d_in[7];
  const float* bv  = (const float*)d_in[8];
  const float* Wo  = (const float*)d_in[9];
  const float* bo  = (const float*)d_in[10];
  const float* Wc  = (const float*)d_in[11];
  const float* bc  = (const float*)d_in[12];
  float* out = (float*)d_out;

  char* ws = (char*)d_ws;
  __hip_bfloat16* omid = (__hip_bfloat16*)ws;                     // 16,777,216 B
  __hip_bfloat16* Wt4  = (__hip_bfloat16*)(ws + 16777216);        // 221,184 B
  __hip_bfloat16* Wqb  = (__hip_bfloat16*)(ws + 16998400);        // 8,192 B
  __hip_bfloat16* Wob  = (__hip_bfloat16*)(ws + 17006592);        // 8,192 B
  __hip_bfloat16* Wkb  = (__hip_bfloat16*)(ws + 17014784);        // 16,384 B
  __hip_bfloat16* Wvb  = (__hip_bfloat16*)(ws + 17031168);        // 16,384 B
  unsigned short* kfb  = (unsigned short*)(ws + 17047552);        // 131,072 B
  unsigned short* vfb  = (unsigned short*)(ws + 17178624);        // 65,536 B

  wprep_kernel<<<dim3(528), 256, 0, stream>>>(Wc, Wq, Wo, Wk, Wv,
                                              Wt4, Wqb, Wob, Wkb, Wvb);
  kv_kernel<<<dim3(B_), 256, 0, stream>>>(mol, Wkb, bk, Wvb, bv, kfb, vfb);
  attn_kernel<<<dim3(MVOX / 64, B_), 512, 0, stream>>>(x, kfb, vfb, bn, Wqb, bq, Wob, bo, omid);
  conv_kernel<<<dim3(256, B_), 256, 0, stream>>>(omid, Wt4, bc, x, out);
}

// Round 18
// 80.479 us; speedup vs baseline: 1.4094x; 1.0821x over previous
//
#include <hip/hip_runtime.h>
#include <hip/hip_bf16.h>

#define B_    4
#define C_    64
#define MVOX  32768      // 32*32*32
#define NATOM 64
#define EMB_  128

typedef __attribute__((ext_vector_type(8)))  __bf16 bf16x8;
typedef __attribute__((ext_vector_type(4)))  float  f32x4;
typedef __attribute__((ext_vector_type(16))) float  f32x16;
typedef __attribute__((ext_vector_type(8)))  unsigned short ushort8;

typedef __attribute__((address_space(1))) const unsigned int gas_u32;
typedef __attribute__((address_space(3))) unsigned int las_u32;

static __device__ __forceinline__ unsigned short bf16u(float f) {
  __hip_bfloat16 h = __float2bfloat16(f);
  return *(unsigned short*)&h;
}

// ---------------------------------------------------------------------------
// Kernel 0+1 merged: blocks 0..463 = weight prep (Wt4/Wqb/Wob);
// blocks 464..467 = K/V projection + attn fragment emission (builds its own
// Wk/Wv MFMA fragments from f32 inputs -> no wprep->kv dependency).
// ---------------------------------------------------------------------------
__global__ __launch_bounds__(256) void prep_kernel(
    const float* __restrict__ Wc, const float* __restrict__ Wq,
    const float* __restrict__ Wo, const float* __restrict__ Wk,
    const float* __restrict__ Wv, const float* __restrict__ mol,
    const float* __restrict__ bk, const float* __restrict__ bv,
    __hip_bfloat16* __restrict__ Wt4, __hip_bfloat16* __restrict__ Wqb,
    __hip_bfloat16* __restrict__ Wob,
    unsigned short* __restrict__ kfb, unsigned short* __restrict__ vfb) {
  __shared__ float smol[NATOM][132];
  __shared__ float res[2][NATOM][68];

  const int tid = threadIdx.x;

  if (blockIdx.x < 464) {
    // ---- weight prep ----
    const int i = blockIdx.x * 256 + tid;
    if (i < 110592) {                                 // conv weights
      const int tap = i >> 12;
      const int coh = (i >> 11) & 1;
      const int ks  = (i >> 9) & 3;
      const int l   = (i >> 3) & 63;
      const int j   = i & 7;
      const int co  = coh * 32 + (l & 31);
      const int ci  = ks * 16 + ((l >> 5) << 3) + j;
      Wt4[i] = __float2bfloat16(Wc[(co * C_ + ci) * 27 + tap]);
    } else if (i < 114688) {                          // Wq (scaled)
      const int i2 = i - 110592;
      const int nf = (i2 >> 10) & 3;
      const int kk = (i2 >> 9) & 1;
      const int l  = (i2 >> 3) & 63;
      const int j  = i2 & 7;
      const int co = nf * 16 + (l & 15);
      const int ci = kk * 32 + ((l >> 4) << 3) + j;
      Wqb[i2] = __float2bfloat16(Wq[co * C_ + ci] * 0.3535533905932738f);
    } else if (i < 118784) {                          // Wo
      const int i3 = i - 114688;
      const int nf = (i3 >> 10) & 3;
      const int kk = (i3 >> 9) & 1;
      const int l  = (i3 >> 3) & 63;
      const int j  = i3 & 7;
      const int co = nf * 16 + (l & 15);
      const int ci = kk * 32 + ((l >> 4) << 3) + j;
      Wob[i3] = __float2bfloat16(Wo[co * C_ + ci]);
    }
    return;
  }

  // ---- K/V projection (4 blocks) ----
  const int b    = blockIdx.x - 464;
  const int lane = tid & 63;
  const int w    = tid >> 6;
  const int kvw  = w >> 1;
  const int ah   = w & 1;

  for (int i = tid; i < 2048; i += 256) {
    const int a = i >> 4, cb = (i & 15) * 8;
    const f32x4 v0 = *(const f32x4*)&mol[(size_t)(b * NATOM + a) * EMB_ + cb];
    const f32x4 v1 = *(const f32x4*)&mol[(size_t)(b * NATOM + a) * EMB_ + cb + 4];
    *(f32x4*)&smol[a][cb]     = v0;
    *(f32x4*)&smol[a][cb + 4] = v1;
  }
  __syncthreads();

  const float* Wsrc = kvw ? Wv : Wk;
  const float* bias = kvw ? bv : bk;

  f32x16 acc[2];
  #pragma unroll
  for (int ch = 0; ch < 2; ++ch)
    #pragma unroll
    for (int r = 0; r < 16; ++r) acc[ch][r] = 0.f;

  const int a = ah * 32 + (lane & 31);
  #pragma unroll
  for (int kk = 0; kk < 8; ++kk) {
    const int e0 = kk * 16 + ((lane >> 5) << 3);
    ushort8 au;
    #pragma unroll
    for (int j = 0; j < 8; ++j) au[j] = bf16u(smol[a][e0 + j]);
    const bf16x8 af = __builtin_bit_cast(bf16x8, au);
    #pragma unroll
    for (int ch = 0; ch < 2; ++ch) {
      // build W B-frag from f32 weights on the fly (L2-hot, 2x16B per frag)
      const int c = ch * 32 + (lane & 31);
      const f32x4 w0 = *(const f32x4*)&Wsrc[c * EMB_ + e0];
      const f32x4 w1 = *(const f32x4*)&Wsrc[c * EMB_ + e0 + 4];
      ushort8 wu;
      #pragma unroll
      for (int j = 0; j < 4; ++j) { wu[j] = bf16u(w0[j]); wu[4 + j] = bf16u(w1[j]); }
      const bf16x8 bf = __builtin_bit_cast(bf16x8, wu);
      acc[ch] = __builtin_amdgcn_mfma_f32_32x32x16_bf16(af, bf, acc[ch], 0, 0, 0);
    }
  }

  #pragma unroll
  for (int ch = 0; ch < 2; ++ch) {
    const int c = ch * 32 + (lane & 31);
    const float bb = bias[c];
    #pragma unroll
    for (int r = 0; r < 16; ++r) {
      const int ar = ah * 32 + (r & 3) + 8 * (r >> 2) + 4 * (lane >> 5);
      res[kvw][ar][c] = acc[ch][r] + bb;
    }
  }
  __syncthreads();

  #pragma unroll
  for (int t = 0; t < 8; ++t) {
    const int idx = t * 256 + tid;
    const int h = idx >> 8, aa = (idx >> 6) & 3, ln = idx & 63;
    const int qd = ln >> 4, l15 = ln & 15;
    ushort8 au;
    if (qd == 0) {
      #pragma unroll
      for (int j = 0; j < 8; ++j) au[j] = bf16u(res[0][aa * 16 + l15][h * 8 + j]);
    } else {
      #pragma unroll
      for (int j = 0; j < 8; ++j) au[j] = 0;
    }
    *(ushort8*)(kfb + (size_t)(((b * 8 + h) * 4 + aa) * 64 + ln) * 8) = au;
  }
  #pragma unroll
  for (int t = 0; t < 4; ++t) {
    const int idx = t * 256 + tid;
    const int h = idx >> 7, s = (idx >> 6) & 1, ln = idx & 63;
    const int qd = ln >> 4, l15 = ln & 15;
    ushort8 au;
    #pragma unroll
    for (int j = 0; j < 8; ++j) {
      const int atom = (2 * s + (j >> 2)) * 16 + qd * 4 + (j & 3);
      au[j] = bf16u(res[1][atom][h * 8 + (l15 & 7)]);
    }
    *(ushort8*)(vfb + (size_t)(((b * 8 + h) * 2 + s) * 64 + ln) * 8) = au;
  }
}

// ---------------------------------------------------------------------------
// Kernel 2: fully-MFMA fused attention, fragment-fed (R14 version, frozen).
// ---------------------------------------------------------------------------
__global__ __launch_bounds__(512, 4) void attn_kernel(
    const float* __restrict__ x,
    const unsigned short* __restrict__ kfb, const unsigned short* __restrict__ vfb,
    const int* __restrict__ batch_nodes,
    const __hip_bfloat16* __restrict__ Wqb, const float* __restrict__ bq,
    const __hip_bfloat16* __restrict__ Wob, const float* __restrict__ bo,
    __hip_bfloat16* __restrict__ omid) {
  __shared__ float buf[64 * C_];     // 16 KB, multi-phase

  const int b    = blockIdx.y;
  const int m0   = blockIdx.x * 64;
  const int tid  = threadIdx.x;
  const int lane = tid & 63;
  const int w    = __builtin_amdgcn_readfirstlane(tid >> 6);   // 0..7
  const int h    = w;
  const int quad = lane >> 4;
  const int l15  = lane & 15;
  const int vq   = w & 3;
  const int cq   = w >> 2;

  bf16x8 kf[4], vf[2];
  #pragma unroll
  for (int a = 0; a < 4; ++a)
    kf[a] = __builtin_bit_cast(bf16x8,
        *(const ushort8*)(kfb + (size_t)(((b * 8 + h) * 4 + a) * 64 + lane) * 8));
  #pragma unroll
  for (int s = 0; s < 2; ++s)
    vf[s] = __builtin_bit_cast(bf16x8,
        *(const ushort8*)(vfb + (size_t)(((b * 8 + h) * 2 + s) * 64 + lane) * 8));

  #pragma unroll
  for (int j = 0; j < 2; ++j) {
    const int cidx = w * 2 + j;
    const int c  = cidx * 4 + (lane >> 4);
    const int v4 = (lane & 15) * 4;
    const float* gsrc = x + (size_t)(b * C_ + c) * MVOX + m0 + v4;
    __builtin_amdgcn_global_load_lds((gas_u32*)gsrc,
                                     (las_u32*)&buf[cidx * 256], 16, 0, 0);
  }
  __syncthreads();

  f32x4 qacc[2];
  {
    bf16x8 af[2];
    #pragma unroll
    for (int kk = 0; kk < 2; ++kk) {
      ushort8 au;
      #pragma unroll
      for (int j = 0; j < 8; ++j)
        au[j] = bf16u(buf[(kk * 32 + quad * 8 + j) * 64 + vq * 16 + l15]);
      af[kk] = __builtin_bit_cast(bf16x8, au);
    }
    #pragma unroll
    for (int nf2 = 0; nf2 < 2; ++nf2) {
      const int nf = cq * 2 + nf2;
      const float bqv = bq[nf * 16 + l15] * 0.3535533905932738f;
      qacc[nf2] = {bqv, bqv, bqv, bqv};
      #pragma unroll
      for (int kk = 0; kk < 2; ++kk) {
        const bf16x8 bf = *(const bf16x8*)(Wqb + (((nf * 2 + kk) << 6) + lane) * 8);
        qacc[nf2] = __builtin_amdgcn_mfma_f32_16x16x32_bf16(af[kk], bf, qacc[nf2], 0, 0, 0);
      }
    }
  }
  __syncthreads();

  unsigned short* qb = (unsigned short*)buf;
  #pragma unroll
  for (int nf2 = 0; nf2 < 2; ++nf2) {
    const int co = (cq * 2 + nf2) * 16 + l15;
    #pragma unroll
    for (int r = 0; r < 4; ++r) {
      const int vr = vq * 16 + quad * 4 + r;
      qb[vr * 64 + (((co >> 3) ^ (vr & 7)) << 3) + (co & 7)] = bf16u(qacc[nf2][r]);
    }
  }
  __syncthreads();

  const int nv = batch_nodes[b];
  unsigned short* ob = (unsigned short*)buf + 4096;

  f32x4 oacc[4];
  #pragma unroll
  for (int v = 0; v < 4; ++v)
    #pragma unroll
    for (int r = 0; r < 4; ++r) oacc[v][r] = 0.f;

  const f32x4 zero4 = {0.f, 0.f, 0.f, 0.f};
  #pragma unroll
  for (int v = 0; v < 4; ++v) {
    const int qrow = v * 16 + l15;
    const bf16x8 qf = __builtin_bit_cast(bf16x8,
        *(const ushort8*)&qb[qrow * 64 + ((h ^ (qrow & 7)) << 3)]);

    f32x4 st[4];
    #pragma unroll
    for (int a = 0; a < 4; ++a)
      st[a] = __builtin_amdgcn_mfma_f32_16x16x32_bf16(kf[a], qf, zero4, 0, 0, 0);

    float m = -1e30f;
    #pragma unroll
    for (int a = 0; a < 4; ++a)
      #pragma unroll
      for (int r = 0; r < 4; ++r) {
        const int atom = a * 16 + quad * 4 + r;
        const float val = (atom < nv) ? st[a][r] : -1e30f;
        st[a][r] = val;
        m = fmaxf(m, val);
      }
    m = fmaxf(m, __shfl_xor(m, 16, 64));
    m = fmaxf(m, __shfl_xor(m, 32, 64));
    float ssum = 0.f;
    #pragma unroll
    for (int a = 0; a < 4; ++a)
      #pragma unroll
      for (int r = 0; r < 4; ++r) {
        const float p = __expf(st[a][r] - m);
        st[a][r] = p;
        ssum += p;
      }
    ssum += __shfl_xor(ssum, 16, 64);
    ssum += __shfl_xor(ssum, 32, 64);
    const float inv = 1.f / ssum;

    #pragma unroll
    for (int s = 0; s < 2; ++s) {
      ushort8 pu;
      #pragma unroll
      for (int j = 0; j < 8; ++j)
        pu[j] = bf16u(st[2 * s + (j >> 2)][j & 3] * inv);
      const bf16x8 pa = __builtin_bit_cast(bf16x8, pu);
      oacc[v] = __builtin_amdgcn_mfma_f32_16x16x32_bf16(pa, vf[s], oacc[v], 0, 0, 0);
    }
  }

  if (l15 < 8) {
    #pragma unroll
    for (int v = 0; v < 4; ++v)
      #pragma unroll
      for (int r = 0; r < 4; ++r) {
        const int vxr = v * 16 + quad * 4 + r;
        ob[vxr * 64 + ((h ^ (vxr & 7)) << 3) + l15] = bf16u(oacc[v][r]);
      }
  }
  __syncthreads();

  {
    bf16x8 af[2];
    #pragma unroll
    for (int kk = 0; kk < 2; ++kk) {
      const int row = vq * 16 + l15;
      af[kk] = __builtin_bit_cast(bf16x8,
          *(const ushort8*)&ob[row * 64 + (((kk * 4 + quad) ^ (row & 7)) << 3)]);
    }
    f32x4 oac[2];
    #pragma unroll
    for (int nf2 = 0; nf2 < 2; ++nf2) {
      const int nf = cq * 2 + nf2;
      const float bov = bo[nf * 16 + l15];
      oac[nf2] = {bov, bov, bov, bov};
      #pragma unroll
      for (int kk = 0; kk < 2; ++kk) {
        const bf16x8 bf = *(const bf16x8*)(Wob + (((nf * 2 + kk) << 6) + lane) * 8);
        oac[nf2] = __builtin_amdgcn_mfma_f32_16x16x32_bf16(af[kk], bf, oac[nf2], 0, 0, 0);
      }
    }
    __syncthreads();
    unsigned short* osb = (unsigned short*)buf;
    #pragma unroll
    for (int nf2 = 0; nf2 < 2; ++nf2) {
      const int co = (cq * 2 + nf2) * 16 + l15;
      #pragma unroll
      for (int r = 0; r < 4; ++r) {
        const int vr = vq * 16 + quad * 4 + r;
        osb[vr * 64 + (((co >> 3) ^ (vr & 7)) << 3) + (co & 7)] =
            bf16u(fmaxf(oac[nf2][r], 0.f));
      }
    }
  }
  __syncthreads();

  *(ushort8*)(omid + (size_t)(b * MVOX + m0) * C_ + tid * 8) =
      *(const ushort8*)&((unsigned short*)buf)[tid * 8];
}

// ---------------------------------------------------------------------------
// Kernel 3: conv3d 3x3x3 circular — R14 structure (best known: 41.4 us),
// plus XCD-aware flattened-grid swizzle (1024 blocks, 1024%8==0 bijective):
// neighboring spatial tiles share 50% halo borders -> same-XCD L2 locality.
// ---------------------------------------------------------------------------
#define LOADB(dst, DX, DY, DZ)                                              \
  {                                                                         \
    const int zp_ = ((lane & 31) + (DZ) + 31) & 31;                         \
    const int sw_ = zp_ & 7;                                                \
    _Pragma("unroll")                                                       \
    for (int ks_ = 0; ks_ < 4; ++ks_) {                                     \
      const int phys_ = (ks_ * 2 + (lane >> 5)) ^ sw_;                      \
      _Pragma("unroll")                                                     \
      for (int i_ = 0; i_ < 2; ++i_) {                                      \
        const int hl_ = (lp + (DX)) * 4 + (i_ + (DY));                      \
        (dst)[i_ * 4 + ks_] =                                               \
            *(const bf16x8*)&halo[((hl_ * 32 + zp_) * 8 + phys_) * 8];      \
      }                                                                     \
    }                                                                       \
  }

#define LOADW(T2)                                                           \
  _Pragma("unroll")                                                         \
  for (int ks_ = 0; ks_ < 4; ++ks_)                                         \
    wf[(T2) % 3][ks_] =                                                     \
        *(const bf16x8*)(Wt4 + ((((T2) * 2 + coh) * 4 + ks_) << 9) + lane * 8);

#define DOMFMA(src, T)                                                      \
  _Pragma("unroll")                                                         \
  for (int ks_ = 0; ks_ < 4; ++ks_)                                         \
    _Pragma("unroll")                                                       \
    for (int i_ = 0; i_ < 2; ++i_)                                          \
      acc[i_] = __builtin_amdgcn_mfma_f32_32x32x16_bf16(                    \
          wf[(T) % 3][ks_], (src)[i_ * 4 + ks_], acc[i_], 0, 0, 0);

__global__ __launch_bounds__(256, 2) void conv_kernel(
    const __hip_bfloat16* __restrict__ omid,
    const __hip_bfloat16* __restrict__ Wt4,
    const float* __restrict__ bc,
    const float* __restrict__ xin,
    float* __restrict__ out) {
  __shared__ __hip_bfloat16 halo[512 * 64];   // 64 KB

  // XCD-aware bijective swizzle of the flattened 1024-block grid
  const int bidsw = (blockIdx.x & 7) * 128 + (blockIdx.x >> 3);
  const int b    = bidsw >> 8;
  const int tile = bidsw & 255;
  const int x0   = (tile >> 4) * 2;
  const int y0   = (tile & 15) * 2;
  const int tid  = threadIdx.x;
  const int lane = tid & 63;
  const int w    = tid >> 6;
  const int coh  = w & 1;
  const int lp   = w >> 1;

  // --- halo staging: 64 chunks x 1KB via global_load_lds ---
  {
    const __hip_bfloat16* src = omid + (size_t)b * MVOX * C_;
    #pragma unroll
    for (int n = 0; n < 16; ++n) {
      const int chunk = w * 16 + n;
      const int li = chunk >> 2;
      const int zb = (chunk & 3) * 8;
      const int gx = (x0 - 1 + (li >> 2)) & 31;
      const int gy = (y0 - 1 + (li & 3)) & 31;
      const __hip_bfloat16* gsrc = src + (size_t)(gx * 1024 + gy * 32 + zb) * C_ + lane * 8;
      __builtin_amdgcn_global_load_lds((gas_u32*)gsrc,
                                       (las_u32*)&halo[chunk * 512], 16, 0, 0);
    }
  }

  // --- weight register ring: taps 0,1 prefetched ---
  bf16x8 wf[3][4];
  LOADW(0);
  LOADW(1);
  __syncthreads();   // halo staged

  f32x16 acc[2];
  #pragma unroll
  for (int i = 0; i < 2; ++i)
    #pragma unroll
    for (int r = 0; r < 16; ++r) acc[i][r] = 0.f;

  // --- B-fragment ring: 3 buffers, 2 taps of lookahead ---
  bf16x8 bR[3][8];
  LOADB(bR[0], 0, 0, 0);   // tap 0
  LOADB(bR[1], 0, 0, 1);   // tap 1

  #pragma unroll
  for (int t = 0; t < 27; ++t) {
    const int tn = t + 2;
    if (tn < 27) {
      LOADB(bR[tn % 3], tn / 9, (tn / 3) % 3, tn % 3);
      LOADW(tn);
    }
    DOMFMA(bR[t % 3], t);
  }

  // --- epilogue: relu(acc+bias) + residual ---
  const int z = lane & 31;
  #pragma unroll
  for (int i = 0; i < 2; ++i) {
    const int gx = x0 + lp, gy = y0 + i;
    #pragma unroll
    for (int r = 0; r < 16; ++r) {
      const int co = coh * 32 + (r & 3) + 8 * (r >> 2) + 4 * (lane >> 5);
      const size_t idx = ((size_t)(b * C_ + co)) * MVOX + gx * 1024 + gy * 32 + z;
      out[idx] = fmaxf(acc[i][r] + bc[co], 0.f) + xin[idx];
    }
  }
}

// ---------------------------------------------------------------------------
extern "C" void kernel_launch(void* const* d_in, const int* in_sizes, int n_in,
                              void* d_out, int out_size, void* d_ws, size_t ws_size,
                              hipStream_t stream) {
  const float* x   = (const float*)d_in[0];
  const float* mol = (const float*)d_in[1];
  const int*   bn  = (const int*)  d_in[2];
  const float* Wq  = (const float*)d_in[3];
  const float* bq  = (const float*)d_in[4];
  const float* Wk  = (const float*)d_in[5];
  const float* bk  = (const float*)d_in[6];
  const float* Wv  = (const float*)d_in[7];
  const float* bv  = (const float*)d_in[8];
  const float* Wo  = (const float*)d_in[9];
  const float* bo  = (const float*)d_in[10];
  const float* Wc  = (const float*)d_in[11];
  const float* bc  = (const float*)d_in[12];
  float* out = (float*)d_out;

  char* ws = (char*)d_ws;
  __hip_bfloat16* omid = (__hip_bfloat16*)ws;                     // 16,777,216 B
  __hip_bfloat16* Wt4  = (__hip_bfloat16*)(ws + 16777216);        // 221,184 B
  __hip_bfloat16* Wqb  = (__hip_bfloat16*)(ws + 16998400);        // 8,192 B
  __hip_bfloat16* Wob  = (__hip_bfloat16*)(ws + 17006592);        // 8,192 B
  unsigned short* kfb  = (unsigned short*)(ws + 17014784);        // 131,072 B
  unsigned short* vfb  = (unsigned short*)(ws + 17145856);        // 65,536 B

  prep_kernel<<<dim3(468), 256, 0, stream>>>(Wc, Wq, Wo, Wk, Wv, mol, bk, bv,
                                             Wt4, Wqb, Wob, kfb, vfb);
  attn_kernel<<<dim3(MVOX / 64, B_), 512, 0, stream>>>(x, kfb, vfb, bn, Wqb, bq, Wob, bo, omid);
  conv_kernel<<<dim3(1024), 256, 0, stream>>>(omid, Wt4, bc, x, out);
}